// Round 4
// baseline (746.799 us; speedup 1.0000x reference)
//
#include <hip/hip_runtime.h>

// BranchingGNN, fp32 math, bf16 gather source. R13 (= R12 resubmit + hardening;
// R12 bench died at container level with no kernel signal — audited for OOB /
// hang hazards, none found).
// Gather kernel was latency-serialized (VALUBusy 62%, HBM 19%, stalls from
// per-row idx-load round-trips + depth-1 DMA pipeline):
//   (a) preload ALL per-wave row state (cnts packed into one u32, idx windows
//       into 4 named registers) before any row DMA -> one drain per wave.
//   (b) cross-row batch pipeline: 4-slot LDS ring, 3 batches (6 dwordx4-DMA
//       instrs) in flight at all times, counted tail waits vmcnt(4/2/0),
//       no drain at row boundaries. Row select via cndmask chain (no
//       runtime-indexed register arrays -> no scratch).
//   (c) NEW: sched_barrier(0) after each counted wait (rule-#18 fence).
// bin/build counting sort + gemm_relu unchanged from R11.

static constexpr int HDIM = 128;
static constexpr int CAP_P = 128;     // item-sources per pattern bucket
static constexpr int CAP_I = 64;      // pattern-sources per item bucket
static constexpr int BSH_P = 8;       // 256 patterns per p-bin
static constexpr int BSH_I = 9;       // 512 items per i-bin
static constexpr int NBIN_MAX = 128;  // assumes m<=32768, n<=65536
static constexpr int CAPB_P = 16384;  // edges per p-bin (mean 12800, +31 sigma)
static constexpr int CAPB_I = 12288;  // edges per i-bin (mean 10240, +20 sigma)

__device__ inline unsigned short f2bf_rne(float x) {
    unsigned u = __float_as_uint(x);
    u += 0x7FFFu + ((u >> 16) & 1u);
    return (unsigned short)(u >> 16);
}
__device__ inline float bf_lo(unsigned u) { return __uint_as_float(u << 16); }
__device__ inline float bf_hi(unsigned u) { return __uint_as_float(u & 0xFFFF0000u); }

// async global->LDS: each lane loads 16 B at its gptr; HW writes lane*16 into lptr.
__device__ __forceinline__ void dma16(const void* g, void* l) {
    __builtin_amdgcn_global_load_lds(
        (const __attribute__((address_space(1))) void*)g,
        (__attribute__((address_space(3))) void*)l, 16, 0, 0);
}
#define WAIT_VM(Nstr) do { \
    asm volatile("s_waitcnt vmcnt(" Nstr ")" ::: "memory"); \
    __builtin_amdgcn_sched_barrier(0); \
} while (0)

// ------------- initial projection: out = relu(X @ W + b), K=64; + bf16 copy ---
template<int K, int R>
__global__ __launch_bounds__(128) void gemm_relu_kernel(
    const float* __restrict__ X, const float* __restrict__ W,
    const float* __restrict__ b, float* __restrict__ out,
    unsigned short* __restrict__ outb, int nrows)
{
    __shared__ float xs[R][K];
    const int j = threadIdx.x;
    const int r0 = blockIdx.x * R;
    const int total = R * K;
    for (int t = j; t < total; t += 128) {
        const int rr = t / K, kk = t % K;
        const int r = r0 + rr;
        xs[rr][kk] = (r < nrows) ? X[(size_t)r * K + kk] : 0.f;
    }
    __syncthreads();
    float acc[R];
    const float bj = b[j];
    #pragma unroll
    for (int i = 0; i < R; ++i) acc[i] = bj;
    #pragma unroll 8
    for (int k = 0; k < K; ++k) {
        const float w = W[k * HDIM + j];
        #pragma unroll
        for (int i = 0; i < R; ++i) acc[i] = fmaf(xs[i][k], w, acc[i]);
    }
    #pragma unroll
    for (int i = 0; i < R; ++i) {
        const int r = r0 + i;
        if (r < nrows) {
            const float v = fmaxf(acc[i], 0.f);
            out[(size_t)r * HDIM + j] = v;
            outb[(size_t)r * HDIM + j] = f2bf_rne(v);
        }
    }
}

// ---------------- phase 1: bin edges by coarse dst range ----------------------
__global__ __launch_bounds__(256) void bin_kernel(
    const int* __restrict__ i_idx, const int* __restrict__ p_idx,
    unsigned* __restrict__ bins_p, unsigned* __restrict__ bins_i,
    int* __restrict__ bcur_p, int* __restrict__ bcur_i, int E)
{
    __shared__ int hp[NBIN_MAX], hi[NBIN_MAX];   // hist, then local cursors
    __shared__ int bp[NBIN_MAX], bi[NBIN_MAX];   // reserved bases
    const int tid = threadIdx.x;
    if (tid < NBIN_MAX) { hp[tid] = 0; hi[tid] = 0; }
    __syncthreads();

    const int base = blockIdx.x * 2048 + tid * 8;
    int ii[8], pp[8];
    const int nv = min(8, E - base);             // valid edges this thread
    if (nv == 8) {
        const int4 a0 = *(const int4*)(i_idx + base);
        const int4 a1 = *(const int4*)(i_idx + base + 4);
        const int4 b0 = *(const int4*)(p_idx + base);
        const int4 b1 = *(const int4*)(p_idx + base + 4);
        ii[0]=a0.x; ii[1]=a0.y; ii[2]=a0.z; ii[3]=a0.w;
        ii[4]=a1.x; ii[5]=a1.y; ii[6]=a1.z; ii[7]=a1.w;
        pp[0]=b0.x; pp[1]=b0.y; pp[2]=b0.z; pp[3]=b0.w;
        pp[4]=b1.x; pp[5]=b1.y; pp[6]=b1.z; pp[7]=b1.w;
    } else {
        #pragma unroll
        for (int k = 0; k < 8; ++k) {
            const int e = base + k;
            ii[k] = (e < E) ? i_idx[e] : 0;
            pp[k] = (e < E) ? p_idx[e] : 0;
        }
    }
    #pragma unroll
    for (int k = 0; k < 8; ++k) {
        if (k < nv) {
            atomicAdd(&hp[pp[k] >> BSH_P], 1);
            atomicAdd(&hi[ii[k] >> BSH_I], 1);
        }
    }
    __syncthreads();
    if (tid < NBIN_MAX) {
        bp[tid] = hp[tid] ? atomicAdd(&bcur_p[tid], hp[tid]) : 0;
    } else {
        const int t = tid - NBIN_MAX;
        bi[t] = hi[t] ? atomicAdd(&bcur_i[t], hi[t]) : 0;
    }
    __syncthreads();
    if (tid < NBIN_MAX) { hp[tid] = 0; hi[tid] = 0; }   // reuse as local cursors
    __syncthreads();
    #pragma unroll
    for (int k = 0; k < 8; ++k) {
        if (k < nv) {
            const int binp = pp[k] >> BSH_P;
            const int posp = bp[binp] + atomicAdd(&hp[binp], 1);
            if (posp < CAPB_P)
                bins_p[(size_t)binp * CAPB_P + posp] =
                    ((unsigned)pp[k] << 16) | (unsigned)(ii[k] & 0xFFFF);
            const int bini = ii[k] >> BSH_I;
            const int posi = bi[bini] + atomicAdd(&hi[bini], 1);
            if (posi < CAPB_I)
                bins_i[(size_t)bini * CAPB_I + posi] =
                    ((unsigned)ii[k] << 16) | (unsigned)(pp[k] & 0xFFFF);
        }
    }
}

// ---------------- phase 2: build buckets, one block per bin -------------------
__global__ __launch_bounds__(256) void build_kernel(
    const unsigned* __restrict__ bins_p, const unsigned* __restrict__ bins_i,
    const int* __restrict__ bcur_p, const int* __restrict__ bcur_i,
    unsigned short* __restrict__ esrc_p, unsigned short* __restrict__ esrc_i,
    int* __restrict__ cnt_p, int* __restrict__ cnt_i, int m, int n, int nbp)
{
    __shared__ int cur[1 << BSH_I];              // 512 covers both sides
    const int tid = threadIdx.x;
    const int bid = blockIdx.x;
    #pragma unroll
    for (int t = tid; t < (1 << BSH_I); t += 256) cur[t] = 0;
    __syncthreads();

    if (bid < nbp) {                             // ---- pattern side ----
        const size_t off = (size_t)bid * CAPB_P;
        const int count = min(bcur_p[bid], CAPB_P);
        int t = tid;
        for (; t + 768 < count; t += 1024) {
            const unsigned u0 = bins_p[off + t];
            const unsigned u1 = bins_p[off + t + 256];
            const unsigned u2 = bins_p[off + t + 512];
            const unsigned u3 = bins_p[off + t + 768];
            #pragma unroll
            for (int q = 0; q < 4; ++q) {
                const unsigned u = (q == 0) ? u0 : (q == 1) ? u1 : (q == 2) ? u2 : u3;
                const int p = (int)(u >> 16);
                const int s = atomicAdd(&cur[p & ((1 << BSH_P) - 1)], 1);
                if (s < CAP_P) esrc_p[(size_t)p * CAP_P + s] = (unsigned short)(u & 0xFFFFu);
            }
        }
        for (; t < count; t += 256) {
            const unsigned u = bins_p[off + t];
            const int p = (int)(u >> 16);
            const int s = atomicAdd(&cur[p & ((1 << BSH_P) - 1)], 1);
            if (s < CAP_P) esrc_p[(size_t)p * CAP_P + s] = (unsigned short)(u & 0xFFFFu);
        }
        __syncthreads();
        const int p_lo = bid << BSH_P;
        for (int q = tid; q < (1 << BSH_P); q += 256) {
            const int p = p_lo + q;
            if (p < m) cnt_p[p] = cur[q];
        }
    } else {                                     // ---- item side ----
        const int b2 = bid - nbp;
        const size_t off = (size_t)b2 * CAPB_I;
        const int count = min(bcur_i[b2], CAPB_I);
        int t = tid;
        for (; t + 768 < count; t += 1024) {
            const unsigned u0 = bins_i[off + t];
            const unsigned u1 = bins_i[off + t + 256];
            const unsigned u2 = bins_i[off + t + 512];
            const unsigned u3 = bins_i[off + t + 768];
            #pragma unroll
            for (int q = 0; q < 4; ++q) {
                const unsigned u = (q == 0) ? u0 : (q == 1) ? u1 : (q == 2) ? u2 : u3;
                const int i = (int)(u >> 16);
                const int s = atomicAdd(&cur[i & ((1 << BSH_I) - 1)], 1);
                if (s < CAP_I) esrc_i[(size_t)i * CAP_I + s] = (unsigned short)(u & 0xFFFFu);
            }
        }
        for (; t < count; t += 256) {
            const unsigned u = bins_i[off + t];
            const int i = (int)(u >> 16);
            const int s = atomicAdd(&cur[i & ((1 << BSH_I) - 1)], 1);
            if (s < CAP_I) esrc_i[(size_t)i * CAP_I + s] = (unsigned short)(u & 0xFFFFu);
        }
        __syncthreads();
        const int i_lo = b2 << BSH_I;
        for (int q = tid; q < (1 << BSH_I); q += 256) {
            const int i = i_lo + q;
            if (i < n) cnt_i[i] = cur[q];
        }
    }
}

// --------- DMA-gather + fp32 GEMM + relu + residual + relu --------------------
// Block = 128 = 2 waves. Wave h owns 4 rows. All row state (cnt, idx window)
// preloaded to registers before any DMA. Cross-row batch pipeline: 4-slot LDS
// ring, up to 3 batches (6 dwordx4 DMA instrs) in flight, tail waits
// vmcnt(4/2/0) -- pipeline never drains at row boundaries.
template<int R, int CAP, bool WRITE_BF>
__global__ __launch_bounds__(128) void gather_update_dma_kernel(
    const unsigned short* __restrict__ srcb, const int* __restrict__ cnts,
    const unsigned short* __restrict__ esrc, const float* __restrict__ W,
    const float* __restrict__ b, float* __restrict__ hdst,
    unsigned short* __restrict__ dstb, int ndst, int zr)
{
    constexpr int NS = 8;             // edges per batch (2 DMA instructions)
    constexpr int R2 = R / 2;         // rows per wave (must be 4: cndmask chain)
    static_assert(R2 == 4, "row-select chain assumes 4 rows/wave");
    __shared__ __align__(16) unsigned stage[2][4][NS][64];  // [wave][ring][slot][lane] 16 KB
    __shared__ float msg[R][HDIM];                          // 4 KB
    const int tid = threadIdx.x, half = tid >> 6, l = tid & 63;
    const int d0 = blockIdx.x * R + half * R2;

    // ---- preload all per-wave row state (registers only, static indexing) ----
    int cArr[R2];
    unsigned widx[R2];
    #pragma unroll
    for (int rr = 0; rr < R2; ++rr) {
        const int d = d0 + rr;
        cArr[rr] = (d < ndst) ? min(cnts[d], CAP) : 0;
    }
    #pragma unroll
    for (int rr = 0; rr < R2; ++rr) {
        const int d = d0 + rr;
        const int dd = (d < ndst) ? d : 0;
        widx[rr] = ((const unsigned*)(esrc + (size_t)dd * CAP))[l & (CAP / 2 - 1)];
    }
    unsigned cntpack = 0, nbpack = 0;
    #pragma unroll
    for (int rr = 0; rr < R2; ++rr) {
        cntpack |= (unsigned)cArr[rr] << (8 * rr);
        nbpack  |= (unsigned)((cArr[rr] + NS - 1) / NS) << (8 * rr);
    }
    const unsigned m0 = widx[0], m1 = widx[1], m2 = widx[2], m3 = widx[3];

    auto nbof = [&](int rr) { return (int)((nbpack >> (8 * rr)) & 255u); };
    auto issue = [&](int row_r, int bb, int slot) {
        unsigned midx = m0;                       // uniform select, no scratch
        midx = (row_r == 1) ? m1 : midx;
        midx = (row_r == 2) ? m2 : midx;
        midx = (row_r == 3) ? m3 : midx;
        const int cnt = (int)((cntpack >> (8 * row_r)) & 255u);
        unsigned* sl = &stage[half][slot][0][0];
        #pragma unroll
        for (int q = 0; q < NS / 4; ++q) {
            // lane l covers row q*4 + (l>>4), bytes (l&15)*16
            const int e = bb * NS + q * 4 + (l >> 4);
            const unsigned w = __shfl(midx, e >> 1, 64);
            int src = (e & 1) ? (int)(w >> 16) : (int)(w & 0xFFFFu);
            src = (e < cnt) ? src : zr;           // sentinel zero row
            dma16(srcb + (size_t)src * HDIM + (l & 15) * 8, sl + q * 256);
        }
    };

    // ---- cross-row pipeline: 3 batches in flight, counted tail waits ----
    int issued = 0, consumed = 0, irow = 0, ib = 0;
    while (irow < R2 && nbof(irow) == 0) ++irow;
    for (int crow = 0; crow < R2; ++crow) {
        float ax = 0.f, ay = 0.f;
        const int nb = nbof(crow);
        for (int cb = 0; cb < nb; ++cb) {
            while (issued - consumed < 3 && irow < R2) {
                issue(irow, ib, issued & 3);
                ++issued; ++ib;
                if (ib >= nbof(irow)) {
                    ib = 0; ++irow;
                    while (irow < R2 && nbof(irow) == 0) ++irow;
                }
            }
            const int fl = issued - consumed;
            if (fl >= 3)      WAIT_VM("4");
            else if (fl == 2) WAIT_VM("2");
            else              WAIT_VM("0");
            const unsigned* sb = &stage[half][consumed & 3][0][0];
            #pragma unroll
            for (int k = 0; k < NS; ++k) {
                const unsigned u = sb[(size_t)k * 64 + l];
                ax += bf_lo(u); ay += bf_hi(u);
            }
            ++consumed;
        }
        ((float2*)msg[half * R2 + crow])[l] = make_float2(ax, ay);
    }
    __syncthreads();

    const int j = tid;                   // column 0..127
    float acc[R];
    const float bj = b[j];
    #pragma unroll
    for (int r = 0; r < R; ++r) acc[r] = bj;
    for (int kk = 0; kk < HDIM / 4; ++kk) {
        const float w0 = W[(kk * 4 + 0) * HDIM + j];
        const float w1 = W[(kk * 4 + 1) * HDIM + j];
        const float w2 = W[(kk * 4 + 2) * HDIM + j];
        const float w3 = W[(kk * 4 + 3) * HDIM + j];
        #pragma unroll
        for (int r = 0; r < R; ++r) {
            const float4 mv = ((const float4*)msg[r])[kk];   // LDS broadcast
            acc[r] = fmaf(mv.x, w0, acc[r]);
            acc[r] = fmaf(mv.y, w1, acc[r]);
            acc[r] = fmaf(mv.z, w2, acc[r]);
            acc[r] = fmaf(mv.w, w3, acc[r]);
        }
    }
    const int db = blockIdx.x * R;
    #pragma unroll
    for (int r = 0; r < R; ++r) {
        const int d = db + r;
        if (d < ndst) {
            const float upd = fmaxf(acc[r], 0.f);
            const float h = hdst[(size_t)d * HDIM + j];
            const float res = fmaxf(h + upd, 0.f);
            hdst[(size_t)d * HDIM + j] = res;
            if (WRITE_BF) dstb[(size_t)d * HDIM + j] = f2bf_rne(res);
        }
    }
}

extern "C" void kernel_launch(void* const* d_in, const int* in_sizes, int n_in,
                              void* d_out, int out_size, void* d_ws, size_t ws_size,
                              hipStream_t stream)
{
    const float* item_feat = (const float*)d_in[0];   // [n,64]
    const float* pat_feat  = (const float*)d_in[1];   // [m,64]
    const int*   i_idx     = (const int*)d_in[2];     // [E]
    const int*   p_idx     = (const int*)d_in[3];     // [E]
    const float* W_item    = (const float*)d_in[4];
    const float* b_item    = (const float*)d_in[5];
    const float* W_pat     = (const float*)d_in[6];
    const float* b_pat     = (const float*)d_in[7];
    const float* W_i2p     = (const float*)d_in[8];
    const float* b_i2p     = (const float*)d_in[9];
    const float* W_p2i     = (const float*)d_in[10];
    const float* b_p2i     = (const float*)d_in[11];

    const int n = in_sizes[0] / 64;
    const int m = in_sizes[1] / 64;
    const int E = in_sizes[2];

    float* h_item = (float*)d_out;                    // [n,128] fp32 (output)
    float* h_pat  = (float*)d_out + (size_t)n * HDIM; // [m,128]

    // ws: [h_item_bf (n+1)*128 u16][h_pat_bf (m+1)*128 u16]
    //     [cnt_p m][cnt_i n][esrc_p m*CAP_P u16][esrc_i n*CAP_I u16]
    //     [bcur_p 128][bcur_i 128][bins_p nbp*CAPB_P u32][bins_i nbi*CAPB_I u32]
    unsigned short* hib = (unsigned short*)d_ws;              // row n = zero row
    unsigned short* hpb = hib + (size_t)(n + 1) * HDIM;       // row m = zero row
    int* cnt_p = (int*)(hpb + (size_t)(m + 1) * HDIM);
    int* cnt_i = cnt_p + m;
    unsigned short* esrc_p = (unsigned short*)(cnt_i + n);
    unsigned short* esrc_i = esrc_p + (size_t)m * CAP_P;
    int* bcur_p = (int*)(esrc_i + (size_t)n * CAP_I);
    int* bcur_i = bcur_p + NBIN_MAX;
    const int nbp = (m + (1 << BSH_P) - 1) >> BSH_P;          // 79 for m=20000
    const int nbi = (n + (1 << BSH_I) - 1) >> BSH_I;          // 98 for n=50000
    unsigned* bins_p = (unsigned*)(bcur_i + NBIN_MAX);
    unsigned* bins_i = bins_p + (size_t)nbp * CAPB_P;

    // zero bin cursors + sentinel rows (ws re-poisoned to 0xAA before every call)
    hipMemsetAsync(bcur_p, 0, 2 * NBIN_MAX * sizeof(int), stream);
    hipMemsetAsync(hib + (size_t)n * HDIM, 0, HDIM * sizeof(unsigned short), stream);
    hipMemsetAsync(hpb + (size_t)m * HDIM, 0, HDIM * sizeof(unsigned short), stream);

    constexpr int RG = 4;
    gemm_relu_kernel<64, RG><<<(n + RG - 1) / RG, 128, 0, stream>>>(
        item_feat, W_item, b_item, h_item, hib, n);
    gemm_relu_kernel<64, RG><<<(m + RG - 1) / RG, 128, 0, stream>>>(
        pat_feat, W_pat, b_pat, h_pat, hpb, m);

    // ---- 2-phase counting-sort bucket build (indices static across rounds) ----
    bin_kernel<<<(E + 2047) / 2048, 256, 0, stream>>>(
        i_idx, p_idx, bins_p, bins_i, bcur_p, bcur_i, E);
    build_kernel<<<nbp + nbi, 256, 0, stream>>>(
        bins_p, bins_i, bcur_p, bcur_i, esrc_p, esrc_i, cnt_p, cnt_i, m, n, nbp);

    // ---- 2 rounds fused DMA-gather+GEMM+update (bf16 gather source) ----
    constexpr int R = 8;
    // round 1
    gather_update_dma_kernel<R, CAP_P, true><<<(m + R - 1) / R, 128, 0, stream>>>(
        hib, cnt_p, esrc_p, W_i2p, b_i2p, h_pat, hpb, m, n);
    gather_update_dma_kernel<R, CAP_I, true><<<(n + R - 1) / R, 128, 0, stream>>>(
        hpb, cnt_i, esrc_i, W_p2i, b_p2i, h_item, hib, n, m);
    // round 2 (final item update needs no bf16 shadow)
    gather_update_dma_kernel<R, CAP_P, true><<<(m + R - 1) / R, 128, 0, stream>>>(
        hib, cnt_p, esrc_p, W_i2p, b_i2p, h_pat, hpb, m, n);
    gather_update_dma_kernel<R, CAP_I, false><<<(n + R - 1) / R, 128, 0, stream>>>(
        hpb, cnt_i, esrc_i, W_p2i, b_p2i, h_item, hib, n, m);
}

// Round 5
// 413.618 us; speedup vs baseline: 1.8055x; 1.8055x over previous
//
#include <hip/hip_runtime.h>

// BranchingGNN, fp32 math, bf16 gather source. R14:
// R13's dynamic cross-row pipeline (while-loop bookkeeping + cndmask row select
// + sched_barrier fences) caused scratch spills: WRITE_SIZE 37.5->125 MB,
// FETCH +54 MB, VALUBusy 62->33%, 2x regression. Same pipeline theory, STATIC
// implementation:
//   - nb forced >= 2 per row (sentinel batches add 0.0) -> branch-free
//     statically-unrolled row transitions; constant depth-2 (3 batches in
//     flight), ring-4 LDS slots, no drain until the wave's final tail.
//   - all row state in statically-indexed register arrays; no dynamic selects,
//     no sched_barrier; WAIT_VM is R11's proven form.
// bin/build counting sort + gemm_relu unchanged.

static constexpr int HDIM = 128;
static constexpr int CAP_P = 128;     // item-sources per pattern bucket
static constexpr int CAP_I = 64;      // pattern-sources per item bucket
static constexpr int BSH_P = 8;       // 256 patterns per p-bin
static constexpr int BSH_I = 9;       // 512 items per i-bin
static constexpr int NBIN_MAX = 128;  // assumes m<=32768, n<=65536
static constexpr int CAPB_P = 16384;  // edges per p-bin (mean 12800, +31 sigma)
static constexpr int CAPB_I = 12288;  // edges per i-bin (mean 10240, +20 sigma)

__device__ inline unsigned short f2bf_rne(float x) {
    unsigned u = __float_as_uint(x);
    u += 0x7FFFu + ((u >> 16) & 1u);
    return (unsigned short)(u >> 16);
}
__device__ inline float bf_lo(unsigned u) { return __uint_as_float(u << 16); }
__device__ inline float bf_hi(unsigned u) { return __uint_as_float(u & 0xFFFF0000u); }

// async global->LDS: each lane loads 16 B at its gptr; HW writes lane*16 into lptr.
__device__ __forceinline__ void dma16(const void* g, void* l) {
    __builtin_amdgcn_global_load_lds(
        (const __attribute__((address_space(1))) void*)g,
        (__attribute__((address_space(3))) void*)l, 16, 0, 0);
}
#define WAIT_VM(Nstr) asm volatile("s_waitcnt vmcnt(" Nstr ")" ::: "memory")

// ------------- initial projection: out = relu(X @ W + b), K=64; + bf16 copy ---
template<int K, int R>
__global__ __launch_bounds__(128) void gemm_relu_kernel(
    const float* __restrict__ X, const float* __restrict__ W,
    const float* __restrict__ b, float* __restrict__ out,
    unsigned short* __restrict__ outb, int nrows)
{
    __shared__ float xs[R][K];
    const int j = threadIdx.x;
    const int r0 = blockIdx.x * R;
    const int total = R * K;
    for (int t = j; t < total; t += 128) {
        const int rr = t / K, kk = t % K;
        const int r = r0 + rr;
        xs[rr][kk] = (r < nrows) ? X[(size_t)r * K + kk] : 0.f;
    }
    __syncthreads();
    float acc[R];
    const float bj = b[j];
    #pragma unroll
    for (int i = 0; i < R; ++i) acc[i] = bj;
    #pragma unroll 8
    for (int k = 0; k < K; ++k) {
        const float w = W[k * HDIM + j];
        #pragma unroll
        for (int i = 0; i < R; ++i) acc[i] = fmaf(xs[i][k], w, acc[i]);
    }
    #pragma unroll
    for (int i = 0; i < R; ++i) {
        const int r = r0 + i;
        if (r < nrows) {
            const float v = fmaxf(acc[i], 0.f);
            out[(size_t)r * HDIM + j] = v;
            outb[(size_t)r * HDIM + j] = f2bf_rne(v);
        }
    }
}

// ---------------- phase 1: bin edges by coarse dst range ----------------------
__global__ __launch_bounds__(256) void bin_kernel(
    const int* __restrict__ i_idx, const int* __restrict__ p_idx,
    unsigned* __restrict__ bins_p, unsigned* __restrict__ bins_i,
    int* __restrict__ bcur_p, int* __restrict__ bcur_i, int E)
{
    __shared__ int hp[NBIN_MAX], hi[NBIN_MAX];   // hist, then local cursors
    __shared__ int bp[NBIN_MAX], bi[NBIN_MAX];   // reserved bases
    const int tid = threadIdx.x;
    if (tid < NBIN_MAX) { hp[tid] = 0; hi[tid] = 0; }
    __syncthreads();

    const int base = blockIdx.x * 2048 + tid * 8;
    int ii[8], pp[8];
    const int nv = min(8, E - base);             // valid edges this thread
    if (nv == 8) {
        const int4 a0 = *(const int4*)(i_idx + base);
        const int4 a1 = *(const int4*)(i_idx + base + 4);
        const int4 b0 = *(const int4*)(p_idx + base);
        const int4 b1 = *(const int4*)(p_idx + base + 4);
        ii[0]=a0.x; ii[1]=a0.y; ii[2]=a0.z; ii[3]=a0.w;
        ii[4]=a1.x; ii[5]=a1.y; ii[6]=a1.z; ii[7]=a1.w;
        pp[0]=b0.x; pp[1]=b0.y; pp[2]=b0.z; pp[3]=b0.w;
        pp[4]=b1.x; pp[5]=b1.y; pp[6]=b1.z; pp[7]=b1.w;
    } else {
        #pragma unroll
        for (int k = 0; k < 8; ++k) {
            const int e = base + k;
            ii[k] = (e < E) ? i_idx[e] : 0;
            pp[k] = (e < E) ? p_idx[e] : 0;
        }
    }
    #pragma unroll
    for (int k = 0; k < 8; ++k) {
        if (k < nv) {
            atomicAdd(&hp[pp[k] >> BSH_P], 1);
            atomicAdd(&hi[ii[k] >> BSH_I], 1);
        }
    }
    __syncthreads();
    if (tid < NBIN_MAX) {
        bp[tid] = hp[tid] ? atomicAdd(&bcur_p[tid], hp[tid]) : 0;
    } else {
        const int t = tid - NBIN_MAX;
        bi[t] = hi[t] ? atomicAdd(&bcur_i[t], hi[t]) : 0;
    }
    __syncthreads();
    if (tid < NBIN_MAX) { hp[tid] = 0; hi[tid] = 0; }   // reuse as local cursors
    __syncthreads();
    #pragma unroll
    for (int k = 0; k < 8; ++k) {
        if (k < nv) {
            const int binp = pp[k] >> BSH_P;
            const int posp = bp[binp] + atomicAdd(&hp[binp], 1);
            if (posp < CAPB_P)
                bins_p[(size_t)binp * CAPB_P + posp] =
                    ((unsigned)pp[k] << 16) | (unsigned)(ii[k] & 0xFFFF);
            const int bini = ii[k] >> BSH_I;
            const int posi = bi[bini] + atomicAdd(&hi[bini], 1);
            if (posi < CAPB_I)
                bins_i[(size_t)bini * CAPB_I + posi] =
                    ((unsigned)ii[k] << 16) | (unsigned)(pp[k] & 0xFFFF);
        }
    }
}

// ---------------- phase 2: build buckets, one block per bin -------------------
__global__ __launch_bounds__(256) void build_kernel(
    const unsigned* __restrict__ bins_p, const unsigned* __restrict__ bins_i,
    const int* __restrict__ bcur_p, const int* __restrict__ bcur_i,
    unsigned short* __restrict__ esrc_p, unsigned short* __restrict__ esrc_i,
    int* __restrict__ cnt_p, int* __restrict__ cnt_i, int m, int n, int nbp)
{
    __shared__ int cur[1 << BSH_I];              // 512 covers both sides
    const int tid = threadIdx.x;
    const int bid = blockIdx.x;
    #pragma unroll
    for (int t = tid; t < (1 << BSH_I); t += 256) cur[t] = 0;
    __syncthreads();

    if (bid < nbp) {                             // ---- pattern side ----
        const size_t off = (size_t)bid * CAPB_P;
        const int count = min(bcur_p[bid], CAPB_P);
        int t = tid;
        for (; t + 768 < count; t += 1024) {
            const unsigned u0 = bins_p[off + t];
            const unsigned u1 = bins_p[off + t + 256];
            const unsigned u2 = bins_p[off + t + 512];
            const unsigned u3 = bins_p[off + t + 768];
            #pragma unroll
            for (int q = 0; q < 4; ++q) {
                const unsigned u = (q == 0) ? u0 : (q == 1) ? u1 : (q == 2) ? u2 : u3;
                const int p = (int)(u >> 16);
                const int s = atomicAdd(&cur[p & ((1 << BSH_P) - 1)], 1);
                if (s < CAP_P) esrc_p[(size_t)p * CAP_P + s] = (unsigned short)(u & 0xFFFFu);
            }
        }
        for (; t < count; t += 256) {
            const unsigned u = bins_p[off + t];
            const int p = (int)(u >> 16);
            const int s = atomicAdd(&cur[p & ((1 << BSH_P) - 1)], 1);
            if (s < CAP_P) esrc_p[(size_t)p * CAP_P + s] = (unsigned short)(u & 0xFFFFu);
        }
        __syncthreads();
        const int p_lo = bid << BSH_P;
        for (int q = tid; q < (1 << BSH_P); q += 256) {
            const int p = p_lo + q;
            if (p < m) cnt_p[p] = cur[q];
        }
    } else {                                     // ---- item side ----
        const int b2 = bid - nbp;
        const size_t off = (size_t)b2 * CAPB_I;
        const int count = min(bcur_i[b2], CAPB_I);
        int t = tid;
        for (; t + 768 < count; t += 1024) {
            const unsigned u0 = bins_i[off + t];
            const unsigned u1 = bins_i[off + t + 256];
            const unsigned u2 = bins_i[off + t + 512];
            const unsigned u3 = bins_i[off + t + 768];
            #pragma unroll
            for (int q = 0; q < 4; ++q) {
                const unsigned u = (q == 0) ? u0 : (q == 1) ? u1 : (q == 2) ? u2 : u3;
                const int i = (int)(u >> 16);
                const int s = atomicAdd(&cur[i & ((1 << BSH_I) - 1)], 1);
                if (s < CAP_I) esrc_i[(size_t)i * CAP_I + s] = (unsigned short)(u & 0xFFFFu);
            }
        }
        for (; t < count; t += 256) {
            const unsigned u = bins_i[off + t];
            const int i = (int)(u >> 16);
            const int s = atomicAdd(&cur[i & ((1 << BSH_I) - 1)], 1);
            if (s < CAP_I) esrc_i[(size_t)i * CAP_I + s] = (unsigned short)(u & 0xFFFFu);
        }
        __syncthreads();
        const int i_lo = b2 << BSH_I;
        for (int q = tid; q < (1 << BSH_I); q += 256) {
            const int i = i_lo + q;
            if (i < n) cnt_i[i] = cur[q];
        }
    }
}

// --------- DMA-gather + fp32 GEMM + relu + residual + relu --------------------
// Block = 128 = 2 waves, 4 rows/wave. All row state preloaded (static indices).
// Static cross-row pipeline: nb>=2 per row (sentinel batches add 0), ring-4 LDS
// slots, constant 3 batches (6 dwordx4-DMA instrs) in flight via WAIT_VM("4"),
// single drain at the wave's very end.
template<int R, int CAP, bool WRITE_BF>
__global__ __launch_bounds__(128) void gather_update_dma_kernel(
    const unsigned short* __restrict__ srcb, const int* __restrict__ cnts,
    const unsigned short* __restrict__ esrc, const float* __restrict__ W,
    const float* __restrict__ b, float* __restrict__ hdst,
    unsigned short* __restrict__ dstb, int ndst, int zr)
{
    constexpr int NS = 8;             // edges per batch (2 DMA instructions)
    constexpr int R2 = R / 2;         // rows per wave
    static_assert(R2 == 4, "skeleton is unrolled for 4 rows/wave");
    __shared__ __align__(16) unsigned stage[2][4][NS][64];  // [wave][ring][slot][lane] 16 KB
    __shared__ float msg[R][HDIM];                          // 4 KB
    const int tid = threadIdx.x, half = tid >> 6, l = tid & 63;
    const int d0 = blockIdx.x * R + half * R2;

    // ---- preload all per-wave row state (static indexing -> registers) ----
    int cA[R2]; unsigned wA[R2]; int nbA[R2];
    #pragma unroll
    for (int rr = 0; rr < R2; ++rr) {
        const int d = d0 + rr;
        cA[rr] = (d < ndst) ? min(cnts[d], CAP) : 0;
    }
    #pragma unroll
    for (int rr = 0; rr < R2; ++rr) {
        const int d = d0 + rr;
        const int dd = (d < ndst) ? d : 0;
        wA[rr] = ((const unsigned*)(esrc + (size_t)dd * CAP))[l & (CAP / 2 - 1)];
    }
    #pragma unroll
    for (int rr = 0; rr < R2; ++rr)
        nbA[rr] = max((cA[rr] + NS - 1) / NS, 2);   // >=2: transitions static

    float ax[R2], ay[R2];
    #pragma unroll
    for (int rr = 0; rr < R2; ++rr) { ax[rr] = 0.f; ay[rr] = 0.f; }

    int ci = 0, cc = 0;                 // issued / consumed batch counters
    auto issueB = [&](unsigned midx, int cnt, int bb) {
        unsigned* sl = &stage[half][ci & 3][0][0];
        #pragma unroll
        for (int q = 0; q < NS / 4; ++q) {
            // lane l covers row q*4 + (l>>4), bytes (l&15)*16
            const int e = bb * NS + q * 4 + (l >> 4);
            const unsigned w = __shfl(midx, e >> 1, 64);
            int src = (e & 1) ? (int)(w >> 16) : (int)(w & 0xFFFFu);
            src = (e < cnt) ? src : zr;           // sentinel zero row
            dma16(srcb + (size_t)src * HDIM + (l & 15) * 8, sl + q * 256);
        }
        ++ci;
    };
    auto consumeB = [&](float& x, float& y) {
        const unsigned* sb = &stage[half][cc & 3][0][0];
        #pragma unroll
        for (int k = 0; k < NS; ++k) {
            const unsigned u = sb[(size_t)k * 64 + l];
            x += bf_lo(u); y += bf_hi(u);
        }
        ++cc;
    };

    // ---- static skeleton: depth-2 across all row boundaries ----
    issueB(wA[0], cA[0], 0); issueB(wA[0], cA[0], 1);

#define ROW_BODY(rr) \
    for (int bb = 2; bb < nbA[rr]; ++bb) { \
        issueB(wA[rr], cA[rr], bb); WAIT_VM("4"); consumeB(ax[rr], ay[rr]); }
#define ROW_TRANS(rr, nx) \
    issueB(wA[nx], cA[nx], 0); WAIT_VM("4"); consumeB(ax[rr], ay[rr]); \
    issueB(wA[nx], cA[nx], 1); WAIT_VM("4"); consumeB(ax[rr], ay[rr]); \
    ((float2*)msg[half * R2 + rr])[l] = make_float2(ax[rr], ay[rr]);

    ROW_BODY(0) ROW_TRANS(0, 1)
    ROW_BODY(1) ROW_TRANS(1, 2)
    ROW_BODY(2) ROW_TRANS(2, 3)
    ROW_BODY(3)
    WAIT_VM("2"); consumeB(ax[3], ay[3]);
    WAIT_VM("0"); consumeB(ax[3], ay[3]);
    ((float2*)msg[half * R2 + 3])[l] = make_float2(ax[3], ay[3]);
#undef ROW_BODY
#undef ROW_TRANS

    __syncthreads();

    const int j = tid;                   // column 0..127
    float acc[R];
    const float bj = b[j];
    #pragma unroll
    for (int r = 0; r < R; ++r) acc[r] = bj;
    for (int kk = 0; kk < HDIM / 4; ++kk) {
        const float w0 = W[(kk * 4 + 0) * HDIM + j];
        const float w1 = W[(kk * 4 + 1) * HDIM + j];
        const float w2 = W[(kk * 4 + 2) * HDIM + j];
        const float w3 = W[(kk * 4 + 3) * HDIM + j];
        #pragma unroll
        for (int r = 0; r < R; ++r) {
            const float4 mv = ((const float4*)msg[r])[kk];   // LDS broadcast
            acc[r] = fmaf(mv.x, w0, acc[r]);
            acc[r] = fmaf(mv.y, w1, acc[r]);
            acc[r] = fmaf(mv.z, w2, acc[r]);
            acc[r] = fmaf(mv.w, w3, acc[r]);
        }
    }
    const int db = blockIdx.x * R;
    #pragma unroll
    for (int r = 0; r < R; ++r) {
        const int d = db + r;
        if (d < ndst) {
            const float upd = fmaxf(acc[r], 0.f);
            const float h = hdst[(size_t)d * HDIM + j];
            const float res = fmaxf(h + upd, 0.f);
            hdst[(size_t)d * HDIM + j] = res;
            if (WRITE_BF) dstb[(size_t)d * HDIM + j] = f2bf_rne(res);
        }
    }
}

extern "C" void kernel_launch(void* const* d_in, const int* in_sizes, int n_in,
                              void* d_out, int out_size, void* d_ws, size_t ws_size,
                              hipStream_t stream)
{
    const float* item_feat = (const float*)d_in[0];   // [n,64]
    const float* pat_feat  = (const float*)d_in[1];   // [m,64]
    const int*   i_idx     = (const int*)d_in[2];     // [E]
    const int*   p_idx     = (const int*)d_in[3];     // [E]
    const float* W_item    = (const float*)d_in[4];
    const float* b_item    = (const float*)d_in[5];
    const float* W_pat     = (const float*)d_in[6];
    const float* b_pat     = (const float*)d_in[7];
    const float* W_i2p     = (const float*)d_in[8];
    const float* b_i2p     = (const float*)d_in[9];
    const float* W_p2i     = (const float*)d_in[10];
    const float* b_p2i     = (const float*)d_in[11];

    const int n = in_sizes[0] / 64;
    const int m = in_sizes[1] / 64;
    const int E = in_sizes[2];

    float* h_item = (float*)d_out;                    // [n,128] fp32 (output)
    float* h_pat  = (float*)d_out + (size_t)n * HDIM; // [m,128]

    // ws: [h_item_bf (n+1)*128 u16][h_pat_bf (m+1)*128 u16]
    //     [cnt_p m][cnt_i n][esrc_p m*CAP_P u16][esrc_i n*CAP_I u16]
    //     [bcur_p 128][bcur_i 128][bins_p nbp*CAPB_P u32][bins_i nbi*CAPB_I u32]
    unsigned short* hib = (unsigned short*)d_ws;              // row n = zero row
    unsigned short* hpb = hib + (size_t)(n + 1) * HDIM;       // row m = zero row
    int* cnt_p = (int*)(hpb + (size_t)(m + 1) * HDIM);
    int* cnt_i = cnt_p + m;
    unsigned short* esrc_p = (unsigned short*)(cnt_i + n);
    unsigned short* esrc_i = esrc_p + (size_t)m * CAP_P;
    int* bcur_p = (int*)(esrc_i + (size_t)n * CAP_I);
    int* bcur_i = bcur_p + NBIN_MAX;
    const int nbp = (m + (1 << BSH_P) - 1) >> BSH_P;          // 79 for m=20000
    const int nbi = (n + (1 << BSH_I) - 1) >> BSH_I;          // 98 for n=50000
    unsigned* bins_p = (unsigned*)(bcur_i + NBIN_MAX);
    unsigned* bins_i = bins_p + (size_t)nbp * CAPB_P;

    // zero bin cursors + sentinel rows (ws re-poisoned to 0xAA before every call)
    hipMemsetAsync(bcur_p, 0, 2 * NBIN_MAX * sizeof(int), stream);
    hipMemsetAsync(hib + (size_t)n * HDIM, 0, HDIM * sizeof(unsigned short), stream);
    hipMemsetAsync(hpb + (size_t)m * HDIM, 0, HDIM * sizeof(unsigned short), stream);

    constexpr int RG = 4;
    gemm_relu_kernel<64, RG><<<(n + RG - 1) / RG, 128, 0, stream>>>(
        item_feat, W_item, b_item, h_item, hib, n);
    gemm_relu_kernel<64, RG><<<(m + RG - 1) / RG, 128, 0, stream>>>(
        pat_feat, W_pat, b_pat, h_pat, hpb, m);

    // ---- 2-phase counting-sort bucket build (indices static across rounds) ----
    bin_kernel<<<(E + 2047) / 2048, 256, 0, stream>>>(
        i_idx, p_idx, bins_p, bins_i, bcur_p, bcur_i, E);
    build_kernel<<<nbp + nbi, 256, 0, stream>>>(
        bins_p, bins_i, bcur_p, bcur_i, esrc_p, esrc_i, cnt_p, cnt_i, m, n, nbp);

    // ---- 2 rounds fused DMA-gather+GEMM+update (bf16 gather source) ----
    constexpr int R = 8;
    // round 1
    gather_update_dma_kernel<R, CAP_P, true><<<(m + R - 1) / R, 128, 0, stream>>>(
        hib, cnt_p, esrc_p, W_i2p, b_i2p, h_pat, hpb, m, n);
    gather_update_dma_kernel<R, CAP_I, true><<<(n + R - 1) / R, 128, 0, stream>>>(
        hpb, cnt_i, esrc_i, W_p2i, b_p2i, h_item, hib, n, m);
    // round 2 (final item update needs no bf16 shadow)
    gather_update_dma_kernel<R, CAP_P, true><<<(m + R - 1) / R, 128, 0, stream>>>(
        hib, cnt_p, esrc_p, W_i2p, b_i2p, h_pat, hpb, m, n);
    gather_update_dma_kernel<R, CAP_I, false><<<(n + R - 1) / R, 128, 0, stream>>>(
        hpb, cnt_i, esrc_i, W_p2i, b_p2i, h_item, hib, n, m);
}

// Round 7
// 357.097 us; speedup vs baseline: 2.0913x; 1.1583x over previous
//
#include <hip/hip_runtime.h>

// BranchingGNN, fp32 gather accum, bf16 gather source + bf16 MFMA update GEMM.
// R16 = R15 resubmit (container died with no kernel signal; audit found no OOB/
// hang/alignment hazard — same infra signature as R12, which ran on resubmit).
// R11/R14 showed gather-pipeline depth is NOT the limiter (70 vs 76 µs);
// VALUBusy ~60% with MfmaUtil 0 => VALU-issue bound. Largest VALU block =
// epilogue GEMM (1024 scalar fmac/wave). This round:
//   - update GEMM moved to mfma_f32_16x16x32_bf16: R=16 rows/block (=MFMA M),
//     msg accumulated fp32 then packed bf16 into LDS; W pre-transposed+converted
//     to bf16 Wt[col][k] by a tiny one-time kernel (2x32 KB, L2-resident).
//     Per wave: 4 N-tiles x 4 K-chunks = 16 MFMA (~160 cy) replaces 2048 cy FMA.
//   - gather reverts to R11's proven per-row depth-2 loop, 8 rows/wave.
//   - LDS 20->12.3 KB (stage 8K + msg 4K).
// bin/build counting sort + gemm_relu unchanged.

static constexpr int HDIM = 128;
static constexpr int CAP_P = 128;     // item-sources per pattern bucket
static constexpr int CAP_I = 64;      // pattern-sources per item bucket
static constexpr int BSH_P = 8;       // 256 patterns per p-bin
static constexpr int BSH_I = 9;       // 512 items per i-bin
static constexpr int NBIN_MAX = 128;  // assumes m<=32768, n<=65536
static constexpr int CAPB_P = 16384;  // edges per p-bin (mean 12800, +31 sigma)
static constexpr int CAPB_I = 12288;  // edges per i-bin (mean 10240, +20 sigma)

using short8 = __attribute__((ext_vector_type(8))) short;
using f32x4  = __attribute__((ext_vector_type(4))) float;

__device__ inline unsigned short f2bf_rne(float x) {
    unsigned u = __float_as_uint(x);
    u += 0x7FFFu + ((u >> 16) & 1u);
    return (unsigned short)(u >> 16);
}
__device__ inline float bf_lo(unsigned u) { return __uint_as_float(u << 16); }
__device__ inline float bf_hi(unsigned u) { return __uint_as_float(u & 0xFFFF0000u); }

// async global->LDS: each lane loads 16 B at its gptr; HW writes lane*16 into lptr.
__device__ __forceinline__ void dma16(const void* g, void* l) {
    __builtin_amdgcn_global_load_lds(
        (const __attribute__((address_space(1))) void*)g,
        (__attribute__((address_space(3))) void*)l, 16, 0, 0);
}
#define WAIT_VM(Nstr) asm volatile("s_waitcnt vmcnt(" Nstr ")" ::: "memory")

// ------------- initial projection: out = relu(X @ W + b), K=64; + bf16 copy ---
template<int K, int R>
__global__ __launch_bounds__(128) void gemm_relu_kernel(
    const float* __restrict__ X, const float* __restrict__ W,
    const float* __restrict__ b, float* __restrict__ out,
    unsigned short* __restrict__ outb, int nrows)
{
    __shared__ float xs[R][K];
    const int j = threadIdx.x;
    const int r0 = blockIdx.x * R;
    const int total = R * K;
    for (int t = j; t < total; t += 128) {
        const int rr = t / K, kk = t % K;
        const int r = r0 + rr;
        xs[rr][kk] = (r < nrows) ? X[(size_t)r * K + kk] : 0.f;
    }
    __syncthreads();
    float acc[R];
    const float bj = b[j];
    #pragma unroll
    for (int i = 0; i < R; ++i) acc[i] = bj;
    #pragma unroll 8
    for (int k = 0; k < K; ++k) {
        const float w = W[k * HDIM + j];
        #pragma unroll
        for (int i = 0; i < R; ++i) acc[i] = fmaf(xs[i][k], w, acc[i]);
    }
    #pragma unroll
    for (int i = 0; i < R; ++i) {
        const int r = r0 + i;
        if (r < nrows) {
            const float v = fmaxf(acc[i], 0.f);
            out[(size_t)r * HDIM + j] = v;
            outb[(size_t)r * HDIM + j] = f2bf_rne(v);
        }
    }
}

// ------------- one-time: W [128k x 128c] fp32 -> Wt [128c x 128k] bf16 --------
// 8 blocks: bit2 of blockIdx selects weight, bits0-1 select 32-row k-chunk.
__global__ __launch_bounds__(128) void wconv_kernel(
    const float* __restrict__ W0, const float* __restrict__ W1,
    unsigned short* __restrict__ Wt0, unsigned short* __restrict__ Wt1)
{
    __shared__ float tile[32][129];
    const int bi = blockIdx.x;
    const float* W = (bi & 4) ? W1 : W0;
    unsigned short* Wt = (bi & 4) ? Wt1 : Wt0;
    const int k0 = (bi & 3) * 32;
    const int tid = threadIdx.x;
    #pragma unroll 8
    for (int r = 0; r < 32; ++r)
        tile[r][tid] = W[(size_t)(k0 + r) * HDIM + tid];
    __syncthreads();
    unsigned* dst = (unsigned*)(Wt + (size_t)tid * HDIM + k0);
    #pragma unroll
    for (int rr = 0; rr < 16; ++rr) {
        const unsigned lo = f2bf_rne(tile[2 * rr][tid]);
        const unsigned hi = f2bf_rne(tile[2 * rr + 1][tid]);
        dst[rr] = (hi << 16) | lo;
    }
}

// ---------------- phase 1: bin edges by coarse dst range ----------------------
__global__ __launch_bounds__(256) void bin_kernel(
    const int* __restrict__ i_idx, const int* __restrict__ p_idx,
    unsigned* __restrict__ bins_p, unsigned* __restrict__ bins_i,
    int* __restrict__ bcur_p, int* __restrict__ bcur_i, int E)
{
    __shared__ int hp[NBIN_MAX], hi[NBIN_MAX];   // hist, then local cursors
    __shared__ int bp[NBIN_MAX], bi[NBIN_MAX];   // reserved bases
    const int tid = threadIdx.x;
    if (tid < NBIN_MAX) { hp[tid] = 0; hi[tid] = 0; }
    __syncthreads();

    const int base = blockIdx.x * 2048 + tid * 8;
    int ii[8], pp[8];
    const int nv = min(8, E - base);             // valid edges this thread
    if (nv == 8) {
        const int4 a0 = *(const int4*)(i_idx + base);
        const int4 a1 = *(const int4*)(i_idx + base + 4);
        const int4 b0 = *(const int4*)(p_idx + base);
        const int4 b1 = *(const int4*)(p_idx + base + 4);
        ii[0]=a0.x; ii[1]=a0.y; ii[2]=a0.z; ii[3]=a0.w;
        ii[4]=a1.x; ii[5]=a1.y; ii[6]=a1.z; ii[7]=a1.w;
        pp[0]=b0.x; pp[1]=b0.y; pp[2]=b0.z; pp[3]=b0.w;
        pp[4]=b1.x; pp[5]=b1.y; pp[6]=b1.z; pp[7]=b1.w;
    } else {
        #pragma unroll
        for (int k = 0; k < 8; ++k) {
            const int e = base + k;
            ii[k] = (e < E) ? i_idx[e] : 0;
            pp[k] = (e < E) ? p_idx[e] : 0;
        }
    }
    #pragma unroll
    for (int k = 0; k < 8; ++k) {
        if (k < nv) {
            atomicAdd(&hp[pp[k] >> BSH_P], 1);
            atomicAdd(&hi[ii[k] >> BSH_I], 1);
        }
    }
    __syncthreads();
    if (tid < NBIN_MAX) {
        bp[tid] = hp[tid] ? atomicAdd(&bcur_p[tid], hp[tid]) : 0;
    } else {
        const int t = tid - NBIN_MAX;
        bi[t] = hi[t] ? atomicAdd(&bcur_i[t], hi[t]) : 0;
    }
    __syncthreads();
    if (tid < NBIN_MAX) { hp[tid] = 0; hi[tid] = 0; }   // reuse as local cursors
    __syncthreads();
    #pragma unroll
    for (int k = 0; k < 8; ++k) {
        if (k < nv) {
            const int binp = pp[k] >> BSH_P;
            const int posp = bp[binp] + atomicAdd(&hp[binp], 1);
            if (posp < CAPB_P)
                bins_p[(size_t)binp * CAPB_P + posp] =
                    ((unsigned)pp[k] << 16) | (unsigned)(ii[k] & 0xFFFF);
            const int bini = ii[k] >> BSH_I;
            const int posi = bi[bini] + atomicAdd(&hi[bini], 1);
            if (posi < CAPB_I)
                bins_i[(size_t)bini * CAPB_I + posi] =
                    ((unsigned)ii[k] << 16) | (unsigned)(pp[k] & 0xFFFF);
        }
    }
}

// ---------------- phase 2: build buckets, one block per bin -------------------
__global__ __launch_bounds__(256) void build_kernel(
    const unsigned* __restrict__ bins_p, const unsigned* __restrict__ bins_i,
    const int* __restrict__ bcur_p, const int* __restrict__ bcur_i,
    unsigned short* __restrict__ esrc_p, unsigned short* __restrict__ esrc_i,
    int* __restrict__ cnt_p, int* __restrict__ cnt_i, int m, int n, int nbp)
{
    __shared__ int cur[1 << BSH_I];              // 512 covers both sides
    const int tid = threadIdx.x;
    const int bid = blockIdx.x;
    #pragma unroll
    for (int t = tid; t < (1 << BSH_I); t += 256) cur[t] = 0;
    __syncthreads();

    if (bid < nbp) {                             // ---- pattern side ----
        const size_t off = (size_t)bid * CAPB_P;
        const int count = min(bcur_p[bid], CAPB_P);
        int t = tid;
        for (; t + 768 < count; t += 1024) {
            const unsigned u0 = bins_p[off + t];
            const unsigned u1 = bins_p[off + t + 256];
            const unsigned u2 = bins_p[off + t + 512];
            const unsigned u3 = bins_p[off + t + 768];
            #pragma unroll
            for (int q = 0; q < 4; ++q) {
                const unsigned u = (q == 0) ? u0 : (q == 1) ? u1 : (q == 2) ? u2 : u3;
                const int p = (int)(u >> 16);
                const int s = atomicAdd(&cur[p & ((1 << BSH_P) - 1)], 1);
                if (s < CAP_P) esrc_p[(size_t)p * CAP_P + s] = (unsigned short)(u & 0xFFFFu);
            }
        }
        for (; t < count; t += 256) {
            const unsigned u = bins_p[off + t];
            const int p = (int)(u >> 16);
            const int s = atomicAdd(&cur[p & ((1 << BSH_P) - 1)], 1);
            if (s < CAP_P) esrc_p[(size_t)p * CAP_P + s] = (unsigned short)(u & 0xFFFFu);
        }
        __syncthreads();
        const int p_lo = bid << BSH_P;
        for (int q = tid; q < (1 << BSH_P); q += 256) {
            const int p = p_lo + q;
            if (p < m) cnt_p[p] = cur[q];
        }
    } else {                                     // ---- item side ----
        const int b2 = bid - nbp;
        const size_t off = (size_t)b2 * CAPB_I;
        const int count = min(bcur_i[b2], CAPB_I);
        int t = tid;
        for (; t + 768 < count; t += 1024) {
            const unsigned u0 = bins_i[off + t];
            const unsigned u1 = bins_i[off + t + 256];
            const unsigned u2 = bins_i[off + t + 512];
            const unsigned u3 = bins_i[off + t + 768];
            #pragma unroll
            for (int q = 0; q < 4; ++q) {
                const unsigned u = (q == 0) ? u0 : (q == 1) ? u1 : (q == 2) ? u2 : u3;
                const int i = (int)(u >> 16);
                const int s = atomicAdd(&cur[i & ((1 << BSH_I) - 1)], 1);
                if (s < CAP_I) esrc_i[(size_t)i * CAP_I + s] = (unsigned short)(u & 0xFFFFu);
            }
        }
        for (; t < count; t += 256) {
            const unsigned u = bins_i[off + t];
            const int i = (int)(u >> 16);
            const int s = atomicAdd(&cur[i & ((1 << BSH_I) - 1)], 1);
            if (s < CAP_I) esrc_i[(size_t)i * CAP_I + s] = (unsigned short)(u & 0xFFFFu);
        }
        __syncthreads();
        const int i_lo = b2 << BSH_I;
        for (int q = tid; q < (1 << BSH_I); q += 256) {
            const int i = i_lo + q;
            if (i < n) cnt_i[i] = cur[q];
        }
    }
}

// --------- DMA-gather + bf16 MFMA GEMM + relu + residual + relu ---------------
// Block = 128 = 2 waves; 16 rows/block (8 per wave). Gather: per-row depth-2
// DMA pipeline (R11-proven), fp32 accumulate, packed to bf16 msg in LDS.
// GEMM: D[16x128] = msg[16x128] @ Wt^T via 16 mfma_f32_16x16x32_bf16 per wave
// (wave h owns N-tiles h*4..h*4+3). Epilogue: +bias, relu, +h, relu, store.
template<int CAP, bool WRITE_BF>
__global__ __launch_bounds__(128) void gather_update_mfma_kernel(
    const unsigned short* __restrict__ srcb, const int* __restrict__ cnts,
    const unsigned short* __restrict__ esrc,
    const unsigned short* __restrict__ Wt,   // bf16 [col][k] (pre-transposed)
    const float* __restrict__ b, float* __restrict__ hdst,
    unsigned short* __restrict__ dstb, int ndst, int zr)
{
    constexpr int NS = 8;             // edges per batch (2 DMA instructions)
    constexpr int R2 = 8;             // rows per wave
    __shared__ __align__(16) unsigned stage[2][2][NS][64];  // 8 KB
    __shared__ __align__(16) unsigned msg[16][64];          // bf16 msg rows, 4 KB
    const int tid = threadIdx.x, half = tid >> 6, l = tid & 63;
    const int db = blockIdx.x * 16;
    const int d0 = db + half * R2;

    // ---- preload all per-wave row state (static indexing -> registers) ----
    int cA[R2]; unsigned wA[R2];
    #pragma unroll
    for (int rr = 0; rr < R2; ++rr) {
        const int d = d0 + rr;
        cA[rr] = (d < ndst) ? min(cnts[d], CAP) : 0;
    }
    #pragma unroll
    for (int rr = 0; rr < R2; ++rr) {
        const int d = d0 + rr;
        const int dd = (d < ndst) ? d : 0;
        wA[rr] = ((const unsigned*)(esrc + (size_t)dd * CAP))[l & (CAP / 2 - 1)];
    }

    // ---- gather: per-row depth-2 pipeline, fp32 accum, bf16 pack to LDS ----
    #pragma unroll
    for (int rr = 0; rr < R2; ++rr) {
        const int cnt = cA[rr];
        const unsigned midx = wA[rr];
        float ax = 0.f, ay = 0.f;
        if (cnt > 0) {
            const int nb = (cnt + NS - 1) / NS;
            auto issue = [&](int bb) {
                unsigned* sl = &stage[half][bb & 1][0][0];
                #pragma unroll
                for (int q = 0; q < NS / 4; ++q) {
                    // lane l covers slot q*4 + (l>>4), bytes (l&15)*16
                    const int e = bb * NS + q * 4 + (l >> 4);
                    const unsigned w = __shfl(midx, e >> 1, 64);
                    int src = (e & 1) ? (int)(w >> 16) : (int)(w & 0xFFFFu);
                    src = (e < cnt) ? src : zr;          // sentinel zero row
                    dma16(srcb + (size_t)src * HDIM + (l & 15) * 8, sl + q * 256);
                }
            };
            issue(0);
            for (int bb = 1; bb < nb; ++bb) {
                issue(bb);                    // 2 batches (4 instrs) in flight
                WAIT_VM("2");
                const unsigned* sb = &stage[half][(bb - 1) & 1][0][0];
                #pragma unroll
                for (int k = 0; k < NS; ++k) {
                    const unsigned u = sb[(size_t)k * 64 + l];
                    ax += bf_lo(u); ay += bf_hi(u);
                }
            }
            WAIT_VM("0");
            const unsigned* sb = &stage[half][(nb - 1) & 1][0][0];
            #pragma unroll
            for (int k = 0; k < NS; ++k) {
                const unsigned u = sb[(size_t)k * 64 + l];
                ax += bf_lo(u); ay += bf_hi(u);
            }
        }
        // pack: cols 2l (lo) and 2l+1 (hi)
        msg[half * R2 + rr][l] =
            ((unsigned)f2bf_rne(ay) << 16) | (unsigned)f2bf_rne(ax);
    }
    __syncthreads();

    // ---- MFMA: wave h computes N-tiles h*4..h*4+3 of D[16x128] ----
    // A-frag (16x32 chunk c): lane holds row l&15, k = c*32 + (l>>4)*8 .. +8
    // B-frag: lane holds col l&15 (+ntile*16), same k range, from Wt[col][k]
    const int nt0 = half * 4;
    const char* abase = (const char*)&msg[0][0] + (l & 15) * 256 + (l >> 4) * 16;
    const unsigned short* wbase = Wt + ((size_t)(l & 15)) * HDIM + (l >> 4) * 8;
    f32x4 acc0 = {0.f, 0.f, 0.f, 0.f};
    f32x4 acc1 = {0.f, 0.f, 0.f, 0.f};
    f32x4 acc2 = {0.f, 0.f, 0.f, 0.f};
    f32x4 acc3 = {0.f, 0.f, 0.f, 0.f};
    #pragma unroll
    for (int c = 0; c < 4; ++c) {
        const short8 a = *(const short8*)(abase + c * 64);
        const short8 b0 = *(const short8*)(wbase + (size_t)(nt0 + 0) * 16 * HDIM + c * 32);
        const short8 b1 = *(const short8*)(wbase + (size_t)(nt0 + 1) * 16 * HDIM + c * 32);
        const short8 b2 = *(const short8*)(wbase + (size_t)(nt0 + 2) * 16 * HDIM + c * 32);
        const short8 b3 = *(const short8*)(wbase + (size_t)(nt0 + 3) * 16 * HDIM + c * 32);
        acc0 = __builtin_amdgcn_mfma_f32_16x16x32_bf16(a, b0, acc0, 0, 0, 0);
        acc1 = __builtin_amdgcn_mfma_f32_16x16x32_bf16(a, b1, acc1, 0, 0, 0);
        acc2 = __builtin_amdgcn_mfma_f32_16x16x32_bf16(a, b2, acc2, 0, 0, 0);
        acc3 = __builtin_amdgcn_mfma_f32_16x16x32_bf16(a, b3, acc3, 0, 0, 0);
    }

    // ---- epilogue: D row = (l>>4)*4 + q, col = ntile*16 + (l&15) ----
    const int rbase = (l >> 4) * 4;
#define EPI(ACC, T) { \
    const int col = (nt0 + (T)) * 16 + (l & 15); \
    const float bias = b[col]; \
    _Pragma("unroll") \
    for (int q = 0; q < 4; ++q) { \
        const int d = db + rbase + q; \
        if (d < ndst) { \
            const float upd = fmaxf(ACC[q] + bias, 0.f); \
            const float h = hdst[(size_t)d * HDIM + col]; \
            const float res = fmaxf(h + upd, 0.f); \
            hdst[(size_t)d * HDIM + col] = res; \
            if (WRITE_BF) dstb[(size_t)d * HDIM + col] = f2bf_rne(res); \
        } \
    } }
    EPI(acc0, 0) EPI(acc1, 1) EPI(acc2, 2) EPI(acc3, 3)
#undef EPI
}

extern "C" void kernel_launch(void* const* d_in, const int* in_sizes, int n_in,
                              void* d_out, int out_size, void* d_ws, size_t ws_size,
                              hipStream_t stream)
{
    const float* item_feat = (const float*)d_in[0];   // [n,64]
    const float* pat_feat  = (const float*)d_in[1];   // [m,64]
    const int*   i_idx     = (const int*)d_in[2];     // [E]
    const int*   p_idx     = (const int*)d_in[3];     // [E]
    const float* W_item    = (const float*)d_in[4];
    const float* b_item    = (const float*)d_in[5];
    const float* W_pat     = (const float*)d_in[6];
    const float* b_pat     = (const float*)d_in[7];
    const float* W_i2p     = (const float*)d_in[8];
    const float* b_i2p     = (const float*)d_in[9];
    const float* W_p2i     = (const float*)d_in[10];
    const float* b_p2i     = (const float*)d_in[11];

    const int n = in_sizes[0] / 64;
    const int m = in_sizes[1] / 64;
    const int E = in_sizes[2];

    float* h_item = (float*)d_out;                    // [n,128] fp32 (output)
    float* h_pat  = (float*)d_out + (size_t)n * HDIM; // [m,128]

    // ws: [h_item_bf (n+1)*128 u16][h_pat_bf (m+1)*128 u16]
    //     [cnt_p m][cnt_i n][esrc_p m*CAP_P u16][esrc_i n*CAP_I u16]
    //     [bcur_p 128][bcur_i 128][bins_p nbp*CAPB_P u32][bins_i nbi*CAPB_I u32]
    //     [wt_i2p 128*128 u16][wt_p2i 128*128 u16]
    unsigned short* hib = (unsigned short*)d_ws;              // row n = zero row
    unsigned short* hpb = hib + (size_t)(n + 1) * HDIM;       // row m = zero row
    int* cnt_p = (int*)(hpb + (size_t)(m + 1) * HDIM);
    int* cnt_i = cnt_p + m;
    unsigned short* esrc_p = (unsigned short*)(cnt_i + n);
    unsigned short* esrc_i = esrc_p + (size_t)m * CAP_P;
    int* bcur_p = (int*)(esrc_i + (size_t)n * CAP_I);
    int* bcur_i = bcur_p + NBIN_MAX;
    const int nbp = (m + (1 << BSH_P) - 1) >> BSH_P;          // 79 for m=20000
    const int nbi = (n + (1 << BSH_I) - 1) >> BSH_I;          // 98 for n=50000
    unsigned* bins_p = (unsigned*)(bcur_i + NBIN_MAX);
    unsigned* bins_i = bins_p + (size_t)nbp * CAPB_P;
    unsigned short* wt_i2p = (unsigned short*)(bins_i + (size_t)nbi * CAPB_I);
    unsigned short* wt_p2i = wt_i2p + HDIM * HDIM;

    // zero bin cursors + sentinel rows (ws re-poisoned to 0xAA before every call)
    hipMemsetAsync(bcur_p, 0, 2 * NBIN_MAX * sizeof(int), stream);
    hipMemsetAsync(hib + (size_t)n * HDIM, 0, HDIM * sizeof(unsigned short), stream);
    hipMemsetAsync(hpb + (size_t)m * HDIM, 0, HDIM * sizeof(unsigned short), stream);

    constexpr int RG = 4;
    gemm_relu_kernel<64, RG><<<(n + RG - 1) / RG, 128, 0, stream>>>(
        item_feat, W_item, b_item, h_item, hib, n);
    gemm_relu_kernel<64, RG><<<(m + RG - 1) / RG, 128, 0, stream>>>(
        pat_feat, W_pat, b_pat, h_pat, hpb, m);

    // one-time bf16 transpose of the two update weights
    wconv_kernel<<<8, 128, 0, stream>>>(W_i2p, W_p2i, wt_i2p, wt_p2i);

    // ---- 2-phase counting-sort bucket build (indices static across rounds) ----
    bin_kernel<<<(E + 2047) / 2048, 256, 0, stream>>>(
        i_idx, p_idx, bins_p, bins_i, bcur_p, bcur_i, E);
    build_kernel<<<nbp + nbi, 256, 0, stream>>>(
        bins_p, bins_i, bcur_p, bcur_i, esrc_p, esrc_i, cnt_p, cnt_i, m, n, nbp);

    // ---- 2 rounds fused DMA-gather + MFMA-update (bf16 gather source) ----
    // round 1
    gather_update_mfma_kernel<CAP_P, true><<<(m + 15) / 16, 128, 0, stream>>>(
        hib, cnt_p, esrc_p, wt_i2p, b_i2p, h_pat, hpb, m, n);
    gather_update_mfma_kernel<CAP_I, true><<<(n + 15) / 16, 128, 0, stream>>>(
        hpb, cnt_i, esrc_i, wt_p2i, b_p2i, h_item, hib, n, m);
    // round 2 (final item update needs no bf16 shadow)
    gather_update_mfma_kernel<CAP_P, true><<<(m + 15) / 16, 128, 0, stream>>>(
        hib, cnt_p, esrc_p, wt_i2p, b_i2p, h_pat, hpb, m, n);
    gather_update_mfma_kernel<CAP_I, false><<<(n + 15) / 16, 128, 0, stream>>>(
        hpb, cnt_i, esrc_i, wt_p2i, b_p2i, h_item, hib, n, m);
}

// Round 8
// 318.421 us; speedup vs baseline: 2.3453x; 1.1215x over previous
//
#include <hip/hip_runtime.h>

// BranchingGNN. R17: R16 (MFMA epilogue, 55 µs gathers) showed no pipe >30% and
// occupancy 39% => TLP-starved latency bound. This round:
//   (a) gather blocks go 128->256 threads (4 waves), 4 rows/wave (was 8): same
//       grid, 2x resident waves. LDS 20 KB -> 7 blocks/CU = 28 waves (87%).
//   (b) msg XOR-swizzle (byte ^= (row&7)<<4) kills the 700K 16-way A-frag
//       ds_read_b128 bank conflicts (256-B row stride, G4 pattern).
//   (c) epilogue via LDS: relu(acc+bias) -> out[16][132] (padded), then
//       row-coalesced float4 read-modify-write of hdst (+bf16 shadow) — kills
//       the 48-vs-37.5 MB write amplification of R16's scattered 64-B stores.
// bin/build counting sort + gemm_relu + wconv unchanged.

static constexpr int HDIM = 128;
static constexpr int CAP_P = 128;     // item-sources per pattern bucket
static constexpr int CAP_I = 64;      // pattern-sources per item bucket
static constexpr int BSH_P = 8;       // 256 patterns per p-bin
static constexpr int BSH_I = 9;       // 512 items per i-bin
static constexpr int NBIN_MAX = 128;  // assumes m<=32768, n<=65536
static constexpr int CAPB_P = 16384;  // edges per p-bin (mean 12800, +31 sigma)
static constexpr int CAPB_I = 12288;  // edges per i-bin (mean 10240, +20 sigma)

using short8 = __attribute__((ext_vector_type(8))) short;
using f32x4  = __attribute__((ext_vector_type(4))) float;

__device__ inline unsigned short f2bf_rne(float x) {
    unsigned u = __float_as_uint(x);
    u += 0x7FFFu + ((u >> 16) & 1u);
    return (unsigned short)(u >> 16);
}
__device__ inline float bf_lo(unsigned u) { return __uint_as_float(u << 16); }
__device__ inline float bf_hi(unsigned u) { return __uint_as_float(u & 0xFFFF0000u); }

// async global->LDS: each lane loads 16 B at its gptr; HW writes lane*16 into lptr.
__device__ __forceinline__ void dma16(const void* g, void* l) {
    __builtin_amdgcn_global_load_lds(
        (const __attribute__((address_space(1))) void*)g,
        (__attribute__((address_space(3))) void*)l, 16, 0, 0);
}
#define WAIT_VM(Nstr) asm volatile("s_waitcnt vmcnt(" Nstr ")" ::: "memory")

// ------------- initial projection: out = relu(X @ W + b), K=64; + bf16 copy ---
template<int K, int R>
__global__ __launch_bounds__(128) void gemm_relu_kernel(
    const float* __restrict__ X, const float* __restrict__ W,
    const float* __restrict__ b, float* __restrict__ out,
    unsigned short* __restrict__ outb, int nrows)
{
    __shared__ float xs[R][K];
    const int j = threadIdx.x;
    const int r0 = blockIdx.x * R;
    const int total = R * K;
    for (int t = j; t < total; t += 128) {
        const int rr = t / K, kk = t % K;
        const int r = r0 + rr;
        xs[rr][kk] = (r < nrows) ? X[(size_t)r * K + kk] : 0.f;
    }
    __syncthreads();
    float acc[R];
    const float bj = b[j];
    #pragma unroll
    for (int i = 0; i < R; ++i) acc[i] = bj;
    #pragma unroll 8
    for (int k = 0; k < K; ++k) {
        const float w = W[k * HDIM + j];
        #pragma unroll
        for (int i = 0; i < R; ++i) acc[i] = fmaf(xs[i][k], w, acc[i]);
    }
    #pragma unroll
    for (int i = 0; i < R; ++i) {
        const int r = r0 + i;
        if (r < nrows) {
            const float v = fmaxf(acc[i], 0.f);
            out[(size_t)r * HDIM + j] = v;
            outb[(size_t)r * HDIM + j] = f2bf_rne(v);
        }
    }
}

// ------------- one-time: W [128k x 128c] fp32 -> Wt [128c x 128k] bf16 --------
__global__ __launch_bounds__(128) void wconv_kernel(
    const float* __restrict__ W0, const float* __restrict__ W1,
    unsigned short* __restrict__ Wt0, unsigned short* __restrict__ Wt1)
{
    __shared__ float tile[32][129];
    const int bi = blockIdx.x;
    const float* W = (bi & 4) ? W1 : W0;
    unsigned short* Wt = (bi & 4) ? Wt1 : Wt0;
    const int k0 = (bi & 3) * 32;
    const int tid = threadIdx.x;
    #pragma unroll 8
    for (int r = 0; r < 32; ++r)
        tile[r][tid] = W[(size_t)(k0 + r) * HDIM + tid];
    __syncthreads();
    unsigned* dst = (unsigned*)(Wt + (size_t)tid * HDIM + k0);
    #pragma unroll
    for (int rr = 0; rr < 16; ++rr) {
        const unsigned lo = f2bf_rne(tile[2 * rr][tid]);
        const unsigned hi = f2bf_rne(tile[2 * rr + 1][tid]);
        dst[rr] = (hi << 16) | lo;
    }
}

// ---------------- phase 1: bin edges by coarse dst range ----------------------
__global__ __launch_bounds__(256) void bin_kernel(
    const int* __restrict__ i_idx, const int* __restrict__ p_idx,
    unsigned* __restrict__ bins_p, unsigned* __restrict__ bins_i,
    int* __restrict__ bcur_p, int* __restrict__ bcur_i, int E)
{
    __shared__ int hp[NBIN_MAX], hi[NBIN_MAX];   // hist, then local cursors
    __shared__ int bp[NBIN_MAX], bi[NBIN_MAX];   // reserved bases
    const int tid = threadIdx.x;
    if (tid < NBIN_MAX) { hp[tid] = 0; hi[tid] = 0; }
    __syncthreads();

    const int base = blockIdx.x * 2048 + tid * 8;
    int ii[8], pp[8];
    const int nv = min(8, E - base);             // valid edges this thread
    if (nv == 8) {
        const int4 a0 = *(const int4*)(i_idx + base);
        const int4 a1 = *(const int4*)(i_idx + base + 4);
        const int4 b0 = *(const int4*)(p_idx + base);
        const int4 b1 = *(const int4*)(p_idx + base + 4);
        ii[0]=a0.x; ii[1]=a0.y; ii[2]=a0.z; ii[3]=a0.w;
        ii[4]=a1.x; ii[5]=a1.y; ii[6]=a1.z; ii[7]=a1.w;
        pp[0]=b0.x; pp[1]=b0.y; pp[2]=b0.z; pp[3]=b0.w;
        pp[4]=b1.x; pp[5]=b1.y; pp[6]=b1.z; pp[7]=b1.w;
    } else {
        #pragma unroll
        for (int k = 0; k < 8; ++k) {
            const int e = base + k;
            ii[k] = (e < E) ? i_idx[e] : 0;
            pp[k] = (e < E) ? p_idx[e] : 0;
        }
    }
    #pragma unroll
    for (int k = 0; k < 8; ++k) {
        if (k < nv) {
            atomicAdd(&hp[pp[k] >> BSH_P], 1);
            atomicAdd(&hi[ii[k] >> BSH_I], 1);
        }
    }
    __syncthreads();
    if (tid < NBIN_MAX) {
        bp[tid] = hp[tid] ? atomicAdd(&bcur_p[tid], hp[tid]) : 0;
    } else {
        const int t = tid - NBIN_MAX;
        bi[t] = hi[t] ? atomicAdd(&bcur_i[t], hi[t]) : 0;
    }
    __syncthreads();
    if (tid < NBIN_MAX) { hp[tid] = 0; hi[tid] = 0; }   // reuse as local cursors
    __syncthreads();
    #pragma unroll
    for (int k = 0; k < 8; ++k) {
        if (k < nv) {
            const int binp = pp[k] >> BSH_P;
            const int posp = bp[binp] + atomicAdd(&hp[binp], 1);
            if (posp < CAPB_P)
                bins_p[(size_t)binp * CAPB_P + posp] =
                    ((unsigned)pp[k] << 16) | (unsigned)(ii[k] & 0xFFFF);
            const int bini = ii[k] >> BSH_I;
            const int posi = bi[bini] + atomicAdd(&hi[bini], 1);
            if (posi < CAPB_I)
                bins_i[(size_t)bini * CAPB_I + posi] =
                    ((unsigned)ii[k] << 16) | (unsigned)(pp[k] & 0xFFFF);
        }
    }
}

// ---------------- phase 2: build buckets, one block per bin -------------------
__global__ __launch_bounds__(256) void build_kernel(
    const unsigned* __restrict__ bins_p, const unsigned* __restrict__ bins_i,
    const int* __restrict__ bcur_p, const int* __restrict__ bcur_i,
    unsigned short* __restrict__ esrc_p, unsigned short* __restrict__ esrc_i,
    int* __restrict__ cnt_p, int* __restrict__ cnt_i, int m, int n, int nbp)
{
    __shared__ int cur[1 << BSH_I];              // 512 covers both sides
    const int tid = threadIdx.x;
    const int bid = blockIdx.x;
    #pragma unroll
    for (int t = tid; t < (1 << BSH_I); t += 256) cur[t] = 0;
    __syncthreads();

    if (bid < nbp) {                             // ---- pattern side ----
        const size_t off = (size_t)bid * CAPB_P;
        const int count = min(bcur_p[bid], CAPB_P);
        int t = tid;
        for (; t + 768 < count; t += 1024) {
            const unsigned u0 = bins_p[off + t];
            const unsigned u1 = bins_p[off + t + 256];
            const unsigned u2 = bins_p[off + t + 512];
            const unsigned u3 = bins_p[off + t + 768];
            #pragma unroll
            for (int q = 0; q < 4; ++q) {
                const unsigned u = (q == 0) ? u0 : (q == 1) ? u1 : (q == 2) ? u2 : u3;
                const int p = (int)(u >> 16);
                const int s = atomicAdd(&cur[p & ((1 << BSH_P) - 1)], 1);
                if (s < CAP_P) esrc_p[(size_t)p * CAP_P + s] = (unsigned short)(u & 0xFFFFu);
            }
        }
        for (; t < count; t += 256) {
            const unsigned u = bins_p[off + t];
            const int p = (int)(u >> 16);
            const int s = atomicAdd(&cur[p & ((1 << BSH_P) - 1)], 1);
            if (s < CAP_P) esrc_p[(size_t)p * CAP_P + s] = (unsigned short)(u & 0xFFFFu);
        }
        __syncthreads();
        const int p_lo = bid << BSH_P;
        for (int q = tid; q < (1 << BSH_P); q += 256) {
            const int p = p_lo + q;
            if (p < m) cnt_p[p] = cur[q];
        }
    } else {                                     // ---- item side ----
        const int b2 = bid - nbp;
        const size_t off = (size_t)b2 * CAPB_I;
        const int count = min(bcur_i[b2], CAPB_I);
        int t = tid;
        for (; t + 768 < count; t += 1024) {
            const unsigned u0 = bins_i[off + t];
            const unsigned u1 = bins_i[off + t + 256];
            const unsigned u2 = bins_i[off + t + 512];
            const unsigned u3 = bins_i[off + t + 768];
            #pragma unroll
            for (int q = 0; q < 4; ++q) {
                const unsigned u = (q == 0) ? u0 : (q == 1) ? u1 : (q == 2) ? u2 : u3;
                const int i = (int)(u >> 16);
                const int s = atomicAdd(&cur[i & ((1 << BSH_I) - 1)], 1);
                if (s < CAP_I) esrc_i[(size_t)i * CAP_I + s] = (unsigned short)(u & 0xFFFFu);
            }
        }
        for (; t < count; t += 256) {
            const unsigned u = bins_i[off + t];
            const int i = (int)(u >> 16);
            const int s = atomicAdd(&cur[i & ((1 << BSH_I) - 1)], 1);
            if (s < CAP_I) esrc_i[(size_t)i * CAP_I + s] = (unsigned short)(u & 0xFFFFu);
        }
        __syncthreads();
        const int i_lo = b2 << BSH_I;
        for (int q = tid; q < (1 << BSH_I); q += 256) {
            const int i = i_lo + q;
            if (i < n) cnt_i[i] = cur[q];
        }
    }
}

// --------- DMA-gather + bf16 MFMA GEMM + relu + residual + relu ---------------
// Block = 256 = 4 waves; 16 rows/block (4 per wave). Gather: per-row depth-2
// DMA pipeline, fp32 accumulate, bf16 pack into XOR-swizzled msg LDS.
// MFMA: wave w computes N-tiles w*2, w*2+1 (8 mfma_f32_16x16x32_bf16).
// Epilogue: relu(acc+bias) -> out LDS [16][132] -> row-coalesced RMW of hdst.
template<int CAP, bool WRITE_BF>
__global__ __launch_bounds__(256) void gather_update_mfma_kernel(
    const unsigned short* __restrict__ srcb, const int* __restrict__ cnts,
    const unsigned short* __restrict__ esrc,
    const unsigned short* __restrict__ Wt,   // bf16 [col][k] (pre-transposed)
    const float* __restrict__ b, float* __restrict__ hdst,
    unsigned short* __restrict__ dstb, int ndst, int zr)
{
    constexpr int NS = 8;             // edges per batch (2 DMA instructions)
    constexpr int R2 = 4;             // rows per wave
    __shared__ __align__(16) unsigned stage[4][2][NS][64];  // 16 KB; reused as out
    __shared__ __align__(16) unsigned msg[16][64];          // bf16 msg, swizzled, 4 KB
    const int tid = threadIdx.x, wid = tid >> 6, l = tid & 63;
    const int db = blockIdx.x * 16;
    const int d0 = db + wid * R2;

    // ---- preload all per-wave row state (static indexing -> registers) ----
    int cA[R2]; unsigned wA[R2];
    #pragma unroll
    for (int rr = 0; rr < R2; ++rr) {
        const int d = d0 + rr;
        cA[rr] = (d < ndst) ? min(cnts[d], CAP) : 0;
    }
    #pragma unroll
    for (int rr = 0; rr < R2; ++rr) {
        const int d = d0 + rr;
        const int dd = (d < ndst) ? d : 0;
        wA[rr] = ((const unsigned*)(esrc + (size_t)dd * CAP))[l & (CAP / 2 - 1)];
    }

    // ---- gather: per-row depth-2 pipeline, fp32 accum, swizzled bf16 pack ----
    #pragma unroll
    for (int rr = 0; rr < R2; ++rr) {
        const int cnt = cA[rr];
        const unsigned midx = wA[rr];
        float ax = 0.f, ay = 0.f;
        if (cnt > 0) {
            const int nb = (cnt + NS - 1) / NS;
            auto issue = [&](int bb) {
                unsigned* sl = &stage[wid][bb & 1][0][0];
                #pragma unroll
                for (int q = 0; q < NS / 4; ++q) {
                    // lane l covers slot q*4 + (l>>4), bytes (l&15)*16
                    const int e = bb * NS + q * 4 + (l >> 4);
                    const unsigned w = __shfl(midx, e >> 1, 64);
                    int src = (e & 1) ? (int)(w >> 16) : (int)(w & 0xFFFFu);
                    src = (e < cnt) ? src : zr;          // sentinel zero row
                    dma16(srcb + (size_t)src * HDIM + (l & 15) * 8, sl + q * 256);
                }
            };
            issue(0);
            for (int bb = 1; bb < nb; ++bb) {
                issue(bb);                    // 2 batches (4 instrs) in flight
                WAIT_VM("2");
                const unsigned* sb = &stage[wid][(bb - 1) & 1][0][0];
                #pragma unroll
                for (int k = 0; k < NS; ++k) {
                    const unsigned u = sb[(size_t)k * 64 + l];
                    ax += bf_lo(u); ay += bf_hi(u);
                }
            }
            WAIT_VM("0");
            const unsigned* sb = &stage[wid][(nb - 1) & 1][0][0];
            #pragma unroll
            for (int k = 0; k < NS; ++k) {
                const unsigned u = sb[(size_t)k * 64 + l];
                ax += bf_lo(u); ay += bf_hi(u);
            }
        }
        // swizzled pack: row r, byte = r*256 + (l*4 ^ ((r&7)<<4))
        const int row = wid * R2 + rr;
        *(unsigned*)((char*)&msg[0][0] + row * 256 + ((l * 4) ^ ((row & 7) << 4))) =
            ((unsigned)f2bf_rne(ay) << 16) | (unsigned)f2bf_rne(ax);
    }
    __syncthreads();

    // ---- MFMA: wave w computes N-tiles w*2, w*2+1 of D[16x128] ----
    // A-frag (16x32 chunk c): lane = row l&15, k-slot byte (c*64+(l>>4)*16),
    // XOR-swizzled by row. B-frag: col l&15 (+tile*16), from Wt[col][k].
    const int nt0 = wid * 2;
    const int arow = l & 15;
    const char* abase = (const char*)&msg[0][0] + arow * 256;
    const int aswz = (arow & 7) << 4;
    const unsigned short* wbase = Wt + ((size_t)(l & 15)) * HDIM + (l >> 4) * 8;
    f32x4 acc0 = {0.f, 0.f, 0.f, 0.f};
    f32x4 acc1 = {0.f, 0.f, 0.f, 0.f};
    #pragma unroll
    for (int c = 0; c < 4; ++c) {
        const short8 a = *(const short8*)(abase + ((c * 64 + (l >> 4) * 16) ^ aswz));
        const short8 b0 = *(const short8*)(wbase + (size_t)(nt0 + 0) * 16 * HDIM + c * 32);
        const short8 b1 = *(const short8*)(wbase + (size_t)(nt0 + 1) * 16 * HDIM + c * 32);
        acc0 = __builtin_amdgcn_mfma_f32_16x16x32_bf16(a, b0, acc0, 0, 0, 0);
        acc1 = __builtin_amdgcn_mfma_f32_16x16x32_bf16(a, b1, acc1, 0, 0, 0);
    }

    // ---- relu(acc+bias) -> out LDS [16][132] (reuses stage) ----
    float* outl = (float*)&stage[0][0][0][0];            // 8448 B <= 16 KB
#define STORE_T(ACC, T) { \
    const int col = (nt0 + (T)) * 16 + (l & 15); \
    const float bias = b[col]; \
    _Pragma("unroll") \
    for (int q = 0; q < 4; ++q) { \
        const int row = (l >> 4) * 4 + q; \
        outl[row * 132 + col] = fmaxf(ACC[q] + bias, 0.f); \
    } }
    STORE_T(acc0, 0) STORE_T(acc1, 1)
#undef STORE_T
    __syncthreads();

    // ---- row-coalesced epilogue: thread t -> row t>>4, cols (t&15)*8..+8 ----
    {
        const int row = tid >> 4, c0 = (tid & 15) * 8;
        const int d = db + row;
        if (d < ndst) {
            const float* orow = &outl[row * 132 + c0];
            const float4 u0 = *(const float4*)(orow);
            const float4 u1 = *(const float4*)(orow + 4);
            float* hrow = &hdst[(size_t)d * HDIM + c0];
            const float4 h0 = *(const float4*)(hrow);
            const float4 h1 = *(const float4*)(hrow + 4);
            float4 r0, r1;
            r0.x = fmaxf(h0.x + u0.x, 0.f); r0.y = fmaxf(h0.y + u0.y, 0.f);
            r0.z = fmaxf(h0.z + u0.z, 0.f); r0.w = fmaxf(h0.w + u0.w, 0.f);
            r1.x = fmaxf(h1.x + u1.x, 0.f); r1.y = fmaxf(h1.y + u1.y, 0.f);
            r1.z = fmaxf(h1.z + u1.z, 0.f); r1.w = fmaxf(h1.w + u1.w, 0.f);
            *(float4*)(hrow) = r0;
            *(float4*)(hrow + 4) = r1;
            if (WRITE_BF) {
                uint4 pb;
                pb.x = ((unsigned)f2bf_rne(r0.y) << 16) | f2bf_rne(r0.x);
                pb.y = ((unsigned)f2bf_rne(r0.w) << 16) | f2bf_rne(r0.z);
                pb.z = ((unsigned)f2bf_rne(r1.y) << 16) | f2bf_rne(r1.x);
                pb.w = ((unsigned)f2bf_rne(r1.w) << 16) | f2bf_rne(r1.z);
                *(uint4*)&dstb[(size_t)d * HDIM + c0] = pb;
            }
        }
    }
}

extern "C" void kernel_launch(void* const* d_in, const int* in_sizes, int n_in,
                              void* d_out, int out_size, void* d_ws, size_t ws_size,
                              hipStream_t stream)
{
    const float* item_feat = (const float*)d_in[0];   // [n,64]
    const float* pat_feat  = (const float*)d_in[1];   // [m,64]
    const int*   i_idx     = (const int*)d_in[2];     // [E]
    const int*   p_idx     = (const int*)d_in[3];     // [E]
    const float* W_item    = (const float*)d_in[4];
    const float* b_item    = (const float*)d_in[5];
    const float* W_pat     = (const float*)d_in[6];
    const float* b_pat     = (const float*)d_in[7];
    const float* W_i2p     = (const float*)d_in[8];
    const float* b_i2p     = (const float*)d_in[9];
    const float* W_p2i     = (const float*)d_in[10];
    const float* b_p2i     = (const float*)d_in[11];

    const int n = in_sizes[0] / 64;
    const int m = in_sizes[1] / 64;
    const int E = in_sizes[2];

    float* h_item = (float*)d_out;                    // [n,128] fp32 (output)
    float* h_pat  = (float*)d_out + (size_t)n * HDIM; // [m,128]

    // ws: [h_item_bf (n+1)*128 u16][h_pat_bf (m+1)*128 u16]
    //     [cnt_p m][cnt_i n][esrc_p m*CAP_P u16][esrc_i n*CAP_I u16]
    //     [bcur_p 128][bcur_i 128][bins_p nbp*CAPB_P u32][bins_i nbi*CAPB_I u32]
    //     [wt_i2p 128*128 u16][wt_p2i 128*128 u16]
    unsigned short* hib = (unsigned short*)d_ws;              // row n = zero row
    unsigned short* hpb = hib + (size_t)(n + 1) * HDIM;       // row m = zero row
    int* cnt_p = (int*)(hpb + (size_t)(m + 1) * HDIM);
    int* cnt_i = cnt_p + m;
    unsigned short* esrc_p = (unsigned short*)(cnt_i + n);
    unsigned short* esrc_i = esrc_p + (size_t)m * CAP_P;
    int* bcur_p = (int*)(esrc_i + (size_t)n * CAP_I);
    int* bcur_i = bcur_p + NBIN_MAX;
    const int nbp = (m + (1 << BSH_P) - 1) >> BSH_P;          // 79 for m=20000
    const int nbi = (n + (1 << BSH_I) - 1) >> BSH_I;          // 98 for n=50000
    unsigned* bins_p = (unsigned*)(bcur_i + NBIN_MAX);
    unsigned* bins_i = bins_p + (size_t)nbp * CAPB_P;
    unsigned short* wt_i2p = (unsigned short*)(bins_i + (size_t)nbi * CAPB_I);
    unsigned short* wt_p2i = wt_i2p + HDIM * HDIM;

    // zero bin cursors + sentinel rows (ws re-poisoned to 0xAA before every call)
    hipMemsetAsync(bcur_p, 0, 2 * NBIN_MAX * sizeof(int), stream);
    hipMemsetAsync(hib + (size_t)n * HDIM, 0, HDIM * sizeof(unsigned short), stream);
    hipMemsetAsync(hpb + (size_t)m * HDIM, 0, HDIM * sizeof(unsigned short), stream);

    constexpr int RG = 4;
    gemm_relu_kernel<64, RG><<<(n + RG - 1) / RG, 128, 0, stream>>>(
        item_feat, W_item, b_item, h_item, hib, n);
    gemm_relu_kernel<64, RG><<<(m + RG - 1) / RG, 128, 0, stream>>>(
        pat_feat, W_pat, b_pat, h_pat, hpb, m);

    // one-time bf16 transpose of the two update weights
    wconv_kernel<<<8, 128, 0, stream>>>(W_i2p, W_p2i, wt_i2p, wt_p2i);

    // ---- 2-phase counting-sort bucket build (indices static across rounds) ----
    bin_kernel<<<(E + 2047) / 2048, 256, 0, stream>>>(
        i_idx, p_idx, bins_p, bins_i, bcur_p, bcur_i, E);
    build_kernel<<<nbp + nbi, 256, 0, stream>>>(
        bins_p, bins_i, bcur_p, bcur_i, esrc_p, esrc_i, cnt_p, cnt_i, m, n, nbp);

    // ---- 2 rounds fused DMA-gather + MFMA-update (bf16 gather source) ----
    // round 1
    gather_update_mfma_kernel<CAP_P, true><<<(m + 15) / 16, 256, 0, stream>>>(
        hib, cnt_p, esrc_p, wt_i2p, b_i2p, h_pat, hpb, m, n);
    gather_update_mfma_kernel<CAP_I, true><<<(n + 15) / 16, 256, 0, stream>>>(
        hpb, cnt_i, esrc_i, wt_p2i, b_p2i, h_item, hib, n, m);
    // round 2 (final item update needs no bf16 shadow)
    gather_update_mfma_kernel<CAP_P, true><<<(m + 15) / 16, 256, 0, stream>>>(
        hib, cnt_p, esrc_p, wt_i2p, b_i2p, h_pat, hpb, m, n);
    gather_update_mfma_kernel<CAP_I, false><<<(n + 15) / 16, 256, 0, stream>>>(
        hpb, cnt_i, esrc_i, wt_p2i, b_p2i, h_item, hib, n, m);
}